// Round 2
// baseline (5829.245 us; speedup 1.0000x reference)
//
#include <hip/hip_runtime.h>
#include <hip/hip_bf16.h>

#ifndef D_FEAT
#define D_FEAT 128
#endif

// ---------------------------------------------------------------------------
// Scatter-add: for each edge e, agg[dst[e]] += h[src[e]] * (WEIGHTED ? ew[e] : 1)
// 32 lanes per edge, float4 per lane (32*4 = 128 features).
// NOTE: reference applies edge_weight ONLY in layer 0; layer 1 is unweighted.
// ---------------------------------------------------------------------------
template <bool WEIGHTED>
__global__ void scatter_kernel(const float* __restrict__ h,
                               const int* __restrict__ src,
                               const int* __restrict__ dst,
                               const float* __restrict__ ew,
                               float* __restrict__ agg,
                               long long total /* = E*32 */) {
    long long tid = (long long)blockIdx.x * blockDim.x + threadIdx.x;
    if (tid >= total) return;
    const int e = (int)(tid >> 5);
    const int c = (int)(tid & 31);

    const int s = src[e];
    const int d = dst[e];
    const float w = WEIGHTED ? ew[e] : 1.0f;

    const float4 v = *reinterpret_cast<const float4*>(h + (long long)s * D_FEAT + c * 4);
    float* p = agg + (long long)d * D_FEAT + c * 4;
    unsafeAtomicAdd(p + 0, v.x * w);
    unsafeAtomicAdd(p + 1, v.y * w);
    unsafeAtomicAdd(p + 2, v.z * w);
    unsafeAtomicAdd(p + 3, v.w * w);
}

// ---------------------------------------------------------------------------
// Fused GEMM: out[n] = relu(agg[n] @ Wr + br + x[n] @ Ws)
// Block = 128 threads (thread = output feature d), 16 nodes per block.
// Node rows staged in LDS; weight rows streamed coalesced (L2-resident).
// Safe to run in-place (X == out): X rows are staged to LDS before any write,
// and blocks own disjoint node ranges.
// ---------------------------------------------------------------------------
#define NODES_PER_BLOCK 16

__global__ void __launch_bounds__(128)
gemm_relu_kernel(const float* __restrict__ A,   // agg [N,128]
                 const float* __restrict__ X,   // h_in [N,128]
                 const float* __restrict__ Wr,  // [128,128] row-major (k, d)
                 const float* __restrict__ Ws,  // [128,128]
                 const float* __restrict__ br,  // [128]
                 float* __restrict__ out,       // [N,128]
                 int N) {
    __shared__ float sA[NODES_PER_BLOCK][D_FEAT];
    __shared__ float sX[NODES_PER_BLOCK][D_FEAT];

    const int d = threadIdx.x;
    const int base = blockIdx.x * NODES_PER_BLOCK;

#pragma unroll
    for (int r = 0; r < NODES_PER_BLOCK; ++r) {
        const int n = base + r;
        if (n < N) {
            sA[r][d] = A[(long long)n * D_FEAT + d];
            sX[r][d] = X[(long long)n * D_FEAT + d];
        }
    }
    __syncthreads();

    const float bias = br[d];
    float acc[NODES_PER_BLOCK];
#pragma unroll
    for (int r = 0; r < NODES_PER_BLOCK; ++r) acc[r] = bias;

    for (int k = 0; k < D_FEAT; ++k) {
        const float wr = Wr[k * D_FEAT + d];
        const float ws = Ws[k * D_FEAT + d];
#pragma unroll
        for (int r = 0; r < NODES_PER_BLOCK; ++r) {
            acc[r] += sA[r][k] * wr + sX[r][k] * ws;
        }
    }

#pragma unroll
    for (int r = 0; r < NODES_PER_BLOCK; ++r) {
        const int n = base + r;
        if (n < N) out[(long long)n * D_FEAT + d] = fmaxf(acc[r], 0.0f);
    }
}

extern "C" void kernel_launch(void* const* d_in, const int* in_sizes, int n_in,
                              void* d_out, int out_size, void* d_ws, size_t ws_size,
                              hipStream_t stream) {
    const float* x  = (const float*)d_in[0];
    const int*   ei = (const int*)d_in[1];     // [2, E] int32 (JAX x64 disabled)
    const float* ew = (const float*)d_in[2];
    const float* Wr0 = (const float*)d_in[3];
    const float* br0 = (const float*)d_in[4];
    const float* Ws0 = (const float*)d_in[5];
    const float* Wr1 = (const float*)d_in[6];
    const float* br1 = (const float*)d_in[7];
    const float* Ws1 = (const float*)d_in[8];

    const int N = in_sizes[0] / D_FEAT;
    const int E = in_sizes[1] / 2;
    const int* src = ei;
    const int* dst = ei + E;

    float* agg = (float*)d_ws;      // N*128 f32 scratch (zeroed per layer)
    float* out = (float*)d_out;     // also holds intermediate h after layer 0

    const long long scat_total = (long long)E * 32;
    const int scat_blocks = (int)((scat_total + 255) / 256);
    const int gemm_blocks = (N + NODES_PER_BLOCK - 1) / NODES_PER_BLOCK;

    // ---- Layer 0 (weighted messages) ----
    hipMemsetAsync(agg, 0, (size_t)N * D_FEAT * 4, stream);
    scatter_kernel<true><<<scat_blocks, 256, 0, stream>>>(x, src, dst, ew, agg, scat_total);
    gemm_relu_kernel<<<gemm_blocks, 128, 0, stream>>>(agg, x, Wr0, Ws0, br0, out, N);

    // ---- Layer 1 (UNweighted messages — reference omits edge_weight here) ----
    hipMemsetAsync(agg, 0, (size_t)N * D_FEAT * 4, stream);
    scatter_kernel<false><<<scat_blocks, 256, 0, stream>>>(out, src, dst, ew, agg, scat_total);
    gemm_relu_kernel<<<gemm_blocks, 128, 0, stream>>>(agg, out, Wr1, Ws1, br1, out, N);
}

// Round 3
// 940.567 us; speedup vs baseline: 6.1976x; 6.1976x over previous
//
#include <hip/hip_runtime.h>
#include <hip/hip_bf16.h>

#ifndef D_FEAT
#define D_FEAT 128
#endif

// ---------------------------------------------------------------------------
// CSR build (per call): counts -> 2-level exclusive scan -> permute edges.
// ---------------------------------------------------------------------------
__global__ void histogram_kernel(const int* __restrict__ dst, int* __restrict__ counts, int E) {
    int e = blockIdx.x * blockDim.x + threadIdx.x;
    if (e < E) atomicAdd(&counts[dst[e]], 1);
}

// Level 1: per-block (1024 elems) sums
__global__ void scan_block_sums(const int* __restrict__ counts, int* __restrict__ bsum, int N) {
    __shared__ int red[256];
    const int b = blockIdx.x, t = threadIdx.x;
    const int base = b * 1024 + t * 4;
    int s = 0;
#pragma unroll
    for (int j = 0; j < 4; ++j) { int i = base + j; if (i < N) s += counts[i]; }
    red[t] = s; __syncthreads();
    for (int off = 128; off > 0; off >>= 1) {
        if (t < off) red[t] += red[t + off];
        __syncthreads();
    }
    if (t == 0) bsum[b] = red[0];
}

// Level 2: single block exclusive-scans block sums (nb <= 128); writes row_ptr[N]=E
__global__ void scan_offsets(int* __restrict__ bsum, int nb, int* __restrict__ row_ptr, int N) {
    __shared__ int sh[128];
    const int t = threadIdx.x;
    const int v = (t < nb) ? bsum[t] : 0;
    sh[t] = v; __syncthreads();
    for (int off = 1; off < 128; off <<= 1) {
        int add = (t >= off) ? sh[t - off] : 0;
        __syncthreads();
        sh[t] += add;
        __syncthreads();
    }
    const int incl = sh[t];
    if (t < nb) bsum[t] = incl - v;         // exclusive block offset
    if (t == nb - 1) row_ptr[N] = incl;     // total == E
}

// Level 3: final per-element exclusive scan -> row_ptr and pos (insert cursors)
__global__ void scan_final(const int* __restrict__ counts, const int* __restrict__ bsum,
                           int* __restrict__ row_ptr, int* __restrict__ pos, int N) {
    __shared__ int tsum[256];
    const int b = blockIdx.x, t = threadIdx.x;
    const int base = b * 1024 + t * 4;
    int c[4]; int s = 0;
#pragma unroll
    for (int j = 0; j < 4; ++j) { int i = base + j; c[j] = (i < N) ? counts[i] : 0; s += c[j]; }
    tsum[t] = s; __syncthreads();
    const int v = s;
    for (int off = 1; off < 256; off <<= 1) {
        int add = (t >= off) ? tsum[t - off] : 0;
        __syncthreads();
        tsum[t] += add;
        __syncthreads();
    }
    int excl = tsum[t] - v + bsum[b];
#pragma unroll
    for (int j = 0; j < 4; ++j) {
        int i = base + j;
        if (i < N) { row_ptr[i] = excl; pos[i] = excl; excl += c[j]; }
    }
}

__global__ void permute_edges(const int* __restrict__ src, const int* __restrict__ dst,
                              const float* __restrict__ ew, int* __restrict__ pos,
                              int* __restrict__ src_s, float* __restrict__ w_s, int E) {
    int e = blockIdx.x * blockDim.x + threadIdx.x;
    if (e >= E) return;
    const int d = dst[e];
    const int p = atomicAdd(&pos[d], 1);
    src_s[p] = src[e];
    w_s[p] = ew[e];
}

// ---------------------------------------------------------------------------
// Gather-aggregate: one wave (64 lanes, float2/lane) per destination node.
// agg[n] = sum_{e in CSR[n]} w_e * h[src_e]   (w=1 for layer 1)
// No atomics, no memset: every row written exactly once.
// ---------------------------------------------------------------------------
template <bool WEIGHTED>
__global__ void __launch_bounds__(256)
gather_aggregate(const float* __restrict__ h,
                 const int* __restrict__ row_ptr,
                 const int* __restrict__ src_s,
                 const float* __restrict__ w_s,
                 float* __restrict__ agg, int N) {
    const int node = blockIdx.x * (blockDim.x >> 6) + (threadIdx.x >> 6);
    const int lane = threadIdx.x & 63;
    if (node >= N) return;
    const int beg = row_ptr[node];
    const int end = row_ptr[node + 1];
    float2 acc = make_float2(0.f, 0.f);
    for (int i = beg; i < end; ++i) {
        const int s = src_s[i];
        const float w = WEIGHTED ? w_s[i] : 1.0f;
        const float2 v = *reinterpret_cast<const float2*>(h + (size_t)s * D_FEAT + lane * 2);
        acc.x += w * v.x;
        acc.y += w * v.y;
    }
    *reinterpret_cast<float2*>(agg + (size_t)node * D_FEAT + lane * 2) = acc;
}

// ---------------------------------------------------------------------------
// Fused GEMM: out[n] = relu(agg[n] @ Wr + br + x[n] @ Ws)
// Safe in-place (X == out): X rows staged in LDS before writes.
// ---------------------------------------------------------------------------
#define NODES_PER_BLOCK 16

__global__ void __launch_bounds__(128)
gemm_relu_kernel(const float* __restrict__ A,
                 const float* __restrict__ X,
                 const float* __restrict__ Wr,
                 const float* __restrict__ Ws,
                 const float* __restrict__ br,
                 float* __restrict__ out,
                 int N) {
    __shared__ float sA[NODES_PER_BLOCK][D_FEAT];
    __shared__ float sX[NODES_PER_BLOCK][D_FEAT];

    const int d = threadIdx.x;
    const int base = blockIdx.x * NODES_PER_BLOCK;

#pragma unroll
    for (int r = 0; r < NODES_PER_BLOCK; ++r) {
        const int n = base + r;
        if (n < N) {
            sA[r][d] = A[(long long)n * D_FEAT + d];
            sX[r][d] = X[(long long)n * D_FEAT + d];
        }
    }
    __syncthreads();

    const float bias = br[d];
    float acc[NODES_PER_BLOCK];
#pragma unroll
    for (int r = 0; r < NODES_PER_BLOCK; ++r) acc[r] = bias;

    for (int k = 0; k < D_FEAT; ++k) {
        const float wr = Wr[k * D_FEAT + d];
        const float ws = Ws[k * D_FEAT + d];
#pragma unroll
        for (int r = 0; r < NODES_PER_BLOCK; ++r) {
            acc[r] += sA[r][k] * wr + sX[r][k] * ws;
        }
    }

#pragma unroll
    for (int r = 0; r < NODES_PER_BLOCK; ++r) {
        const int n = base + r;
        if (n < N) out[(long long)n * D_FEAT + d] = fmaxf(acc[r], 0.0f);
    }
}

extern "C" void kernel_launch(void* const* d_in, const int* in_sizes, int n_in,
                              void* d_out, int out_size, void* d_ws, size_t ws_size,
                              hipStream_t stream) {
    const float* x  = (const float*)d_in[0];
    const int*   ei = (const int*)d_in[1];     // [2, E] int32 (JAX x64 disabled)
    const float* ew = (const float*)d_in[2];
    const float* Wr0 = (const float*)d_in[3];
    const float* br0 = (const float*)d_in[4];
    const float* Ws0 = (const float*)d_in[5];
    const float* Wr1 = (const float*)d_in[6];
    const float* br1 = (const float*)d_in[7];
    const float* Ws1 = (const float*)d_in[8];

    const int N = in_sizes[0] / D_FEAT;
    const int E = in_sizes[1] / 2;
    const int* src = ei;
    const int* dst = ei + E;

    // ---- workspace carve-up (all 16B aligned) ----
    char* w = (char*)d_ws;
    auto carve = [&](size_t bytes) { char* p = w; w += (bytes + 15) & ~(size_t)15; return p; };
    float* agg     = (float*)carve((size_t)N * D_FEAT * 4);  // 51.2 MB
    int*   counts  = (int*)  carve((size_t)N * 4);
    int*   row_ptr = (int*)  carve((size_t)(N + 1) * 4);
    int*   pos     = (int*)  carve((size_t)N * 4);
    int*   bsum    = (int*)  carve(128 * 4);
    int*   src_s   = (int*)  carve((size_t)E * 4);           // 6.4 MB
    float* w_s     = (float*)carve((size_t)E * 4);           // 6.4 MB

    float* out = (float*)d_out;  // also holds intermediate h after layer 0

    const int nb = (N + 1023) / 1024;  // scan blocks (98 for N=100k, must be <=128)
    const int eb = (E + 255) / 256;
    const int gather_blocks = (N + 3) / 4;           // 4 nodes per 256-thread block
    const int gemm_blocks = (N + NODES_PER_BLOCK - 1) / NODES_PER_BLOCK;

    // ---- CSR build (reused by both layers) ----
    hipMemsetAsync(counts, 0, (size_t)N * 4, stream);
    histogram_kernel<<<eb, 256, 0, stream>>>(dst, counts, E);
    scan_block_sums<<<nb, 256, 0, stream>>>(counts, bsum, N);
    scan_offsets<<<1, 128, 0, stream>>>(bsum, nb, row_ptr, N);
    scan_final<<<nb, 256, 0, stream>>>(counts, bsum, row_ptr, pos, N);
    permute_edges<<<eb, 256, 0, stream>>>(src, dst, ew, pos, src_s, w_s, E);

    // ---- Layer 0 (weighted messages) ----
    gather_aggregate<true><<<gather_blocks, 256, 0, stream>>>(x, row_ptr, src_s, w_s, agg, N);
    gemm_relu_kernel<<<gemm_blocks, 128, 0, stream>>>(agg, x, Wr0, Ws0, br0, out, N);

    // ---- Layer 1 (unweighted — reference omits edge_weight here) ----
    gather_aggregate<false><<<gather_blocks, 256, 0, stream>>>(out, row_ptr, src_s, w_s, agg, N);
    gemm_relu_kernel<<<gemm_blocks, 128, 0, stream>>>(agg, out, Wr1, Ws1, br1, out, N);
}

// Round 4
// 772.784 us; speedup vs baseline: 7.5432x; 1.2171x over previous
//
#include <hip/hip_runtime.h>
#include <hip/hip_bf16.h>

#ifndef D_FEAT
#define D_FEAT 128
#endif

// ---------------------------------------------------------------------------
// CSR build (per call): counts -> 2-level exclusive scan -> permute edges.
// ---------------------------------------------------------------------------
__global__ void histogram_kernel(const int* __restrict__ dst, int* __restrict__ counts, int E) {
    int e = blockIdx.x * blockDim.x + threadIdx.x;
    if (e < E) atomicAdd(&counts[dst[e]], 1);
}

// Level 1: per-block (1024 elems) sums
__global__ void scan_block_sums(const int* __restrict__ counts, int* __restrict__ bsum, int N) {
    __shared__ int red[256];
    const int b = blockIdx.x, t = threadIdx.x;
    const int base = b * 1024 + t * 4;
    int s = 0;
#pragma unroll
    for (int j = 0; j < 4; ++j) { int i = base + j; if (i < N) s += counts[i]; }
    red[t] = s; __syncthreads();
    for (int off = 128; off > 0; off >>= 1) {
        if (t < off) red[t] += red[t + off];
        __syncthreads();
    }
    if (t == 0) bsum[b] = red[0];
}

// Level 2: single block exclusive-scans block sums (nb <= 128); writes row_ptr[N]=E
__global__ void scan_offsets(int* __restrict__ bsum, int nb, int* __restrict__ row_ptr, int N) {
    __shared__ int sh[128];
    const int t = threadIdx.x;
    const int v = (t < nb) ? bsum[t] : 0;
    sh[t] = v; __syncthreads();
    for (int off = 1; off < 128; off <<= 1) {
        int add = (t >= off) ? sh[t - off] : 0;
        __syncthreads();
        sh[t] += add;
        __syncthreads();
    }
    const int incl = sh[t];
    if (t < nb) bsum[t] = incl - v;         // exclusive block offset
    if (t == nb - 1) row_ptr[N] = incl;     // total == E
}

// Level 3: final per-element exclusive scan -> row_ptr and pos (insert cursors)
__global__ void scan_final(const int* __restrict__ counts, const int* __restrict__ bsum,
                           int* __restrict__ row_ptr, int* __restrict__ pos, int N) {
    __shared__ int tsum[256];
    const int b = blockIdx.x, t = threadIdx.x;
    const int base = b * 1024 + t * 4;
    int c[4]; int s = 0;
#pragma unroll
    for (int j = 0; j < 4; ++j) { int i = base + j; c[j] = (i < N) ? counts[i] : 0; s += c[j]; }
    tsum[t] = s; __syncthreads();
    const int v = s;
    for (int off = 1; off < 256; off <<= 1) {
        int add = (t >= off) ? tsum[t - off] : 0;
        __syncthreads();
        tsum[t] += add;
        __syncthreads();
    }
    int excl = tsum[t] - v + bsum[b];
#pragma unroll
    for (int j = 0; j < 4; ++j) {
        int i = base + j;
        if (i < N) { row_ptr[i] = excl; pos[i] = excl; excl += c[j]; }
    }
}

__global__ void permute_edges(const int* __restrict__ src, const int* __restrict__ dst,
                              const float* __restrict__ ew, int* __restrict__ pos,
                              int* __restrict__ src_s, float* __restrict__ w_s, int E) {
    int e = blockIdx.x * blockDim.x + threadIdx.x;
    if (e >= E) return;
    const int d = dst[e];
    const int p = atomicAdd(&pos[d], 1);
    src_s[p] = src[e];
    w_s[p] = ew[e];
}

// ---------------------------------------------------------------------------
// Gather-aggregate: one wave (64 lanes, float2/lane) per destination node.
// ---------------------------------------------------------------------------
template <bool WEIGHTED>
__global__ void __launch_bounds__(256)
gather_aggregate(const float* __restrict__ h,
                 const int* __restrict__ row_ptr,
                 const int* __restrict__ src_s,
                 const float* __restrict__ w_s,
                 float* __restrict__ agg, int N) {
    const int node = blockIdx.x * (blockDim.x >> 6) + (threadIdx.x >> 6);
    const int lane = threadIdx.x & 63;
    if (node >= N) return;
    const int beg = row_ptr[node];
    const int end = row_ptr[node + 1];
    float2 acc = make_float2(0.f, 0.f);
    for (int i = beg; i < end; ++i) {
        const int s = src_s[i];
        const float w = WEIGHTED ? w_s[i] : 1.0f;
        const float2 v = *reinterpret_cast<const float2*>(h + (size_t)s * D_FEAT + lane * 2);
        acc.x += w * v.x;
        acc.y += w * v.y;
    }
    *reinterpret_cast<float2*>(agg + (size_t)node * D_FEAT + lane * 2) = acc;
}

// ---------------------------------------------------------------------------
// Fused GEMM: out = relu([A | X] @ [Wr ; Ws] + br), K=256.
// BM=128 nodes x BN=128 feats x BK=32; 256 threads, 8x8 register tile each.
// sA stored transposed [k][node] (stride 132: 16B-aligned, conflict-light).
// Inner loop per k: 4x ds_read_b128 + 64x v_fma_f32.
// In-place safe (X == out): block reads only its own rows, writes them last.
// ---------------------------------------------------------------------------
#define BK 32
#define LDSPAD 132

__global__ void __launch_bounds__(256)
gemm_relu_kernel(const float* __restrict__ A,
                 const float* __restrict__ X,
                 const float* __restrict__ Wr,
                 const float* __restrict__ Ws,
                 const float* __restrict__ br,
                 float* __restrict__ out,
                 int N) {
    __shared__ float sA[BK][LDSPAD];
    __shared__ float sW[BK][LDSPAD];

    const int tid = threadIdx.x;
    const int tx = tid & 15;   // col group: cols tx*8 .. tx*8+7
    const int ty = tid >> 4;   // row group: rows ty*8 .. ty*8+7
    const int row0 = blockIdx.x * 128;

    float acc[8][8];
#pragma unroll
    for (int i = 0; i < 8; ++i)
#pragma unroll
        for (int j = 0; j < 8; ++j) acc[i][j] = 0.f;

    for (int chunk = 0; chunk < 8; ++chunk) {
        const float* __restrict__ Asrc = (chunk < 4) ? A : X;
        const float* __restrict__ Wsrc = (chunk < 4) ? Wr : Ws;
        const int k0 = (chunk & 3) * BK;

        // Stage A-tile transposed: 128 nodes x 32 k. Thread loads 4x float4.
#pragma unroll
        for (int p = 0; p < 4; ++p) {
            const int node = p * 32 + (tid >> 3);
            const int kk = (tid & 7) * 4;
            const int gnode = row0 + node;
            float4 v = make_float4(0.f, 0.f, 0.f, 0.f);
            if (gnode < N)
                v = *reinterpret_cast<const float4*>(Asrc + (size_t)gnode * D_FEAT + k0 + kk);
            sA[kk + 0][node] = v.x;
            sA[kk + 1][node] = v.y;
            sA[kk + 2][node] = v.z;
            sA[kk + 3][node] = v.w;
        }
        // Stage W-tile: 32 k x 128 cols. Thread loads 4x float4 of one k-row.
        {
            const int k = tid >> 3;
            const int c0 = (tid & 7) * 16;
            const float* wrow = Wsrc + (size_t)(k0 + k) * D_FEAT + c0;
#pragma unroll
            for (int j = 0; j < 4; ++j) {
                *reinterpret_cast<float4*>(&sW[k][c0 + j * 4]) =
                    *reinterpret_cast<const float4*>(wrow + j * 4);
            }
        }
        __syncthreads();

#pragma unroll
        for (int k = 0; k < BK; ++k) {
            float a[8], wv[8];
            *reinterpret_cast<float4*>(&a[0]) = *reinterpret_cast<const float4*>(&sA[k][ty * 8]);
            *reinterpret_cast<float4*>(&a[4]) = *reinterpret_cast<const float4*>(&sA[k][ty * 8 + 4]);
            *reinterpret_cast<float4*>(&wv[0]) = *reinterpret_cast<const float4*>(&sW[k][tx * 8]);
            *reinterpret_cast<float4*>(&wv[4]) = *reinterpret_cast<const float4*>(&sW[k][tx * 8 + 4]);
#pragma unroll
            for (int i = 0; i < 8; ++i)
#pragma unroll
                for (int j = 0; j < 8; ++j)
                    acc[i][j] += a[i] * wv[j];
        }
        __syncthreads();
    }

    // Epilogue: bias + relu + store (each thread: 8 rows x 8 cols)
    float bias[8];
    *reinterpret_cast<float4*>(&bias[0]) = *reinterpret_cast<const float4*>(br + tx * 8);
    *reinterpret_cast<float4*>(&bias[4]) = *reinterpret_cast<const float4*>(br + tx * 8 + 4);

#pragma unroll
    for (int i = 0; i < 8; ++i) {
        const int gnode = row0 + ty * 8 + i;
        if (gnode >= N) continue;
        float o[8];
#pragma unroll
        for (int j = 0; j < 8; ++j) o[j] = fmaxf(acc[i][j] + bias[j], 0.f);
        float* dst = out + (size_t)gnode * D_FEAT + tx * 8;
        *reinterpret_cast<float4*>(dst + 0) = *reinterpret_cast<float4*>(&o[0]);
        *reinterpret_cast<float4*>(dst + 4) = *reinterpret_cast<float4*>(&o[4]);
    }
}

extern "C" void kernel_launch(void* const* d_in, const int* in_sizes, int n_in,
                              void* d_out, int out_size, void* d_ws, size_t ws_size,
                              hipStream_t stream) {
    const float* x  = (const float*)d_in[0];
    const int*   ei = (const int*)d_in[1];     // [2, E] int32 (JAX x64 disabled)
    const float* ew = (const float*)d_in[2];
    const float* Wr0 = (const float*)d_in[3];
    const float* br0 = (const float*)d_in[4];
    const float* Ws0 = (const float*)d_in[5];
    const float* Wr1 = (const float*)d_in[6];
    const float* br1 = (const float*)d_in[7];
    const float* Ws1 = (const float*)d_in[8];

    const int N = in_sizes[0] / D_FEAT;
    const int E = in_sizes[1] / 2;
    const int* src = ei;
    const int* dst = ei + E;

    // ---- workspace carve-up (all 16B aligned) ----
    char* w = (char*)d_ws;
    auto carve = [&](size_t bytes) { char* p = w; w += (bytes + 15) & ~(size_t)15; return p; };
    float* agg     = (float*)carve((size_t)N * D_FEAT * 4);  // 51.2 MB
    int*   counts  = (int*)  carve((size_t)N * 4);
    int*   row_ptr = (int*)  carve((size_t)(N + 1) * 4);
    int*   pos     = (int*)  carve((size_t)N * 4);
    int*   bsum    = (int*)  carve(128 * 4);
    int*   src_s   = (int*)  carve((size_t)E * 4);           // 6.4 MB
    float* w_s     = (float*)carve((size_t)E * 4);           // 6.4 MB

    float* out = (float*)d_out;  // also holds intermediate h after layer 0

    const int nb = (N + 1023) / 1024;  // scan blocks (98 for N=100k, <=128)
    const int eb = (E + 255) / 256;
    const int gather_blocks = (N + 3) / 4;
    const int gemm_blocks = (N + 127) / 128;

    // ---- CSR build (reused by both layers) ----
    hipMemsetAsync(counts, 0, (size_t)N * 4, stream);
    histogram_kernel<<<eb, 256, 0, stream>>>(dst, counts, E);
    scan_block_sums<<<nb, 256, 0, stream>>>(counts, bsum, N);
    scan_offsets<<<1, 128, 0, stream>>>(bsum, nb, row_ptr, N);
    scan_final<<<nb, 256, 0, stream>>>(counts, bsum, row_ptr, pos, N);
    permute_edges<<<eb, 256, 0, stream>>>(src, dst, ew, pos, src_s, w_s, E);

    // ---- Layer 0 (weighted messages) ----
    gather_aggregate<true><<<gather_blocks, 256, 0, stream>>>(x, row_ptr, src_s, w_s, agg, N);
    gemm_relu_kernel<<<gemm_blocks, 256, 0, stream>>>(agg, x, Wr0, Ws0, br0, out, N);

    // ---- Layer 1 (unweighted — reference omits edge_weight here) ----
    gather_aggregate<false><<<gather_blocks, 256, 0, stream>>>(out, row_ptr, src_s, w_s, agg, N);
    gemm_relu_kernel<<<gemm_blocks, 256, 0, stream>>>(agg, out, Wr1, Ws1, br1, out, N);
}

// Round 5
// 651.339 us; speedup vs baseline: 8.9496x; 1.1865x over previous
//
#include <hip/hip_runtime.h>
#include <hip/hip_bf16.h>

#ifndef D_FEAT
#define D_FEAT 128
#endif

// ---------------- bf16 helpers (RN-even) ----------------
__device__ __forceinline__ unsigned short f2bf(float f) {
    union { float f; unsigned u; } v; v.f = f;
    unsigned r = v.u + 0x7FFF + ((v.u >> 16) & 1);
    return (unsigned short)(r >> 16);
}
__device__ __forceinline__ float bf2f_lo(unsigned u) {
    union { unsigned u; float f; } v; v.u = u << 16; return v.f;
}
__device__ __forceinline__ float bf2f_hi(unsigned u) {
    union { unsigned u; float f; } v; v.u = u & 0xFFFF0000u; return v.f;
}

// ---------------------------------------------------------------------------
// CSR build (per call): counts -> 2-level exclusive scan -> permute edges.
// ---------------------------------------------------------------------------
__global__ void histogram_kernel(const int* __restrict__ dst, int* __restrict__ counts, int E) {
    int e = blockIdx.x * blockDim.x + threadIdx.x;
    if (e < E) atomicAdd(&counts[dst[e]], 1);
}

__global__ void scan_block_sums(const int* __restrict__ counts, int* __restrict__ bsum, int N) {
    __shared__ int red[256];
    const int b = blockIdx.x, t = threadIdx.x;
    const int base = b * 1024 + t * 4;
    int s = 0;
#pragma unroll
    for (int j = 0; j < 4; ++j) { int i = base + j; if (i < N) s += counts[i]; }
    red[t] = s; __syncthreads();
    for (int off = 128; off > 0; off >>= 1) {
        if (t < off) red[t] += red[t + off];
        __syncthreads();
    }
    if (t == 0) bsum[b] = red[0];
}

__global__ void scan_offsets(int* __restrict__ bsum, int nb, int* __restrict__ row_ptr, int N) {
    __shared__ int sh[128];
    const int t = threadIdx.x;
    const int v = (t < nb) ? bsum[t] : 0;
    sh[t] = v; __syncthreads();
    for (int off = 1; off < 128; off <<= 1) {
        int add = (t >= off) ? sh[t - off] : 0;
        __syncthreads();
        sh[t] += add;
        __syncthreads();
    }
    const int incl = sh[t];
    if (t < nb) bsum[t] = incl - v;
    if (t == nb - 1) row_ptr[N] = incl;
}

__global__ void scan_final(const int* __restrict__ counts, const int* __restrict__ bsum,
                           int* __restrict__ row_ptr, int* __restrict__ pos, int N) {
    __shared__ int tsum[256];
    const int b = blockIdx.x, t = threadIdx.x;
    const int base = b * 1024 + t * 4;
    int c[4]; int s = 0;
#pragma unroll
    for (int j = 0; j < 4; ++j) { int i = base + j; c[j] = (i < N) ? counts[i] : 0; s += c[j]; }
    tsum[t] = s; __syncthreads();
    const int v = s;
    for (int off = 1; off < 256; off <<= 1) {
        int add = (t >= off) ? tsum[t - off] : 0;
        __syncthreads();
        tsum[t] += add;
        __syncthreads();
    }
    int excl = tsum[t] - v + bsum[b];
#pragma unroll
    for (int j = 0; j < 4; ++j) {
        int i = base + j;
        if (i < N) { row_ptr[i] = excl; pos[i] = excl; excl += c[j]; }
    }
}

__global__ void permute_edges(const int* __restrict__ src, const int* __restrict__ dst,
                              const float* __restrict__ ew, int* __restrict__ pos,
                              int* __restrict__ src_s, float* __restrict__ w_s, int E) {
    int e = blockIdx.x * blockDim.x + threadIdx.x;
    if (e >= E) return;
    const int d = dst[e];
    const int p = atomicAdd(&pos[d], 1);
    src_s[p] = src[e];
    w_s[p] = ew[e];
}

// ---------------------------------------------------------------------------
// fp32 -> bf16 bulk convert (thread = 4 elems)
// ---------------------------------------------------------------------------
__global__ void convert_f32_bf16(const float* __restrict__ in,
                                 unsigned short* __restrict__ outb, int n4) {
    int i = blockIdx.x * blockDim.x + threadIdx.x;
    if (i >= n4) return;
    float4 v = reinterpret_cast<const float4*>(in)[i];
    unsigned lo = (unsigned)f2bf(v.x) | ((unsigned)f2bf(v.y) << 16);
    unsigned hi = (unsigned)f2bf(v.z) | ((unsigned)f2bf(v.w) << 16);
    reinterpret_cast<uint2*>(outb)[i] = make_uint2(lo, hi);
}

// ---------------------------------------------------------------------------
// Gather-aggregate (bf16 rows, fp32 accumulate, bf16 agg out).
// One wave per node; lane covers 2 feats (4B/lane -> 256B/row, coalesced).
// ---------------------------------------------------------------------------
template <bool WEIGHTED>
__global__ void __launch_bounds__(256)
gather_aggregate(const unsigned short* __restrict__ hb,   // bf16 [N,128]
                 const int* __restrict__ row_ptr,
                 const int* __restrict__ src_s,
                 const float* __restrict__ w_s,
                 unsigned short* __restrict__ aggb,       // bf16 [N,128]
                 int N) {
    const int node = blockIdx.x * 4 + (threadIdx.x >> 6);
    const int lane = threadIdx.x & 63;
    if (node >= N) return;
    const int beg = row_ptr[node];
    const int end = row_ptr[node + 1];
    float ax = 0.f, ay = 0.f;
    int i = beg;
    for (; i + 2 <= end; i += 2) {
        const int s0 = src_s[i], s1 = src_s[i + 1];
        const float w0 = WEIGHTED ? w_s[i] : 1.0f;
        const float w1 = WEIGHTED ? w_s[i + 1] : 1.0f;
        const unsigned u0 = *reinterpret_cast<const unsigned*>(hb + (size_t)s0 * D_FEAT + lane * 2);
        const unsigned u1 = *reinterpret_cast<const unsigned*>(hb + (size_t)s1 * D_FEAT + lane * 2);
        ax += w0 * bf2f_lo(u0) + w1 * bf2f_lo(u1);
        ay += w0 * bf2f_hi(u0) + w1 * bf2f_hi(u1);
    }
    if (i < end) {
        const int s0 = src_s[i];
        const float w0 = WEIGHTED ? w_s[i] : 1.0f;
        const unsigned u0 = *reinterpret_cast<const unsigned*>(hb + (size_t)s0 * D_FEAT + lane * 2);
        ax += w0 * bf2f_lo(u0);
        ay += w0 * bf2f_hi(u0);
    }
    const unsigned o = (unsigned)f2bf(ax) | ((unsigned)f2bf(ay) << 16);
    *reinterpret_cast<unsigned*>(aggb + (size_t)node * D_FEAT + lane * 2) = o;
}

// ---------------------------------------------------------------------------
// Fused GEMM: out = relu([A | X] @ [Wr ; Ws] + br), K=256.
// A is bf16 (converted during LDS staging); X fp32. 8x8 register tiles.
// Optionally dual-writes bf16 copy of the output (layer 0 -> next gather).
// In-place safe (X == out): block reads only its own rows, writes them last.
// ---------------------------------------------------------------------------
#define BK 32
#define LDSPAD 132

template <bool WRITE_BF16>
__global__ void __launch_bounds__(256)
gemm_relu_kernel(const unsigned short* __restrict__ Ab,  // bf16 agg [N,128]
                 const float* __restrict__ X,            // fp32 [N,128]
                 const float* __restrict__ Wr,
                 const float* __restrict__ Ws,
                 const float* __restrict__ br,
                 float* __restrict__ out,
                 unsigned short* __restrict__ hb_out,    // bf16 out copy (or null)
                 int N) {
    __shared__ float sA[BK][LDSPAD];
    __shared__ float sW[BK][LDSPAD];

    const int tid = threadIdx.x;
    const int tx = tid & 15;
    const int ty = tid >> 4;
    const int row0 = blockIdx.x * 128;

    float acc[8][8];
#pragma unroll
    for (int i = 0; i < 8; ++i)
#pragma unroll
        for (int j = 0; j < 8; ++j) acc[i][j] = 0.f;

    for (int chunk = 0; chunk < 8; ++chunk) {
        const bool isA = (chunk < 4);
        const float* __restrict__ Wsrc = isA ? Wr : Ws;
        const int k0 = (chunk & 3) * BK;

        // Stage A-tile transposed: 128 nodes x 32 k.
#pragma unroll
        for (int p = 0; p < 4; ++p) {
            const int node = p * 32 + (tid >> 3);
            const int kk = (tid & 7) * 4;
            const int gnode = row0 + node;
            float v0 = 0.f, v1 = 0.f, v2 = 0.f, v3 = 0.f;
            if (gnode < N) {
                if (isA) {
                    const uint2 u = *reinterpret_cast<const uint2*>(
                        Ab + (size_t)gnode * D_FEAT + k0 + kk);
                    v0 = bf2f_lo(u.x); v1 = bf2f_hi(u.x);
                    v2 = bf2f_lo(u.y); v3 = bf2f_hi(u.y);
                } else {
                    const float4 v = *reinterpret_cast<const float4*>(
                        X + (size_t)gnode * D_FEAT + k0 + kk);
                    v0 = v.x; v1 = v.y; v2 = v.z; v3 = v.w;
                }
            }
            sA[kk + 0][node] = v0;
            sA[kk + 1][node] = v1;
            sA[kk + 2][node] = v2;
            sA[kk + 3][node] = v3;
        }
        // Stage W-tile: 32 k x 128 cols.
        {
            const int k = tid >> 3;
            const int c0 = (tid & 7) * 16;
            const float* wrow = Wsrc + (size_t)(k0 + k) * D_FEAT + c0;
#pragma unroll
            for (int j = 0; j < 4; ++j) {
                *reinterpret_cast<float4*>(&sW[k][c0 + j * 4]) =
                    *reinterpret_cast<const float4*>(wrow + j * 4);
            }
        }
        __syncthreads();

#pragma unroll
        for (int k = 0; k < BK; ++k) {
            float a[8], wv[8];
            *reinterpret_cast<float4*>(&a[0]) = *reinterpret_cast<const float4*>(&sA[k][ty * 8]);
            *reinterpret_cast<float4*>(&a[4]) = *reinterpret_cast<const float4*>(&sA[k][ty * 8 + 4]);
            *reinterpret_cast<float4*>(&wv[0]) = *reinterpret_cast<const float4*>(&sW[k][tx * 8]);
            *reinterpret_cast<float4*>(&wv[4]) = *reinterpret_cast<const float4*>(&sW[k][tx * 8 + 4]);
#pragma unroll
            for (int i = 0; i < 8; ++i)
#pragma unroll
                for (int j = 0; j < 8; ++j)
                    acc[i][j] += a[i] * wv[j];
        }
        __syncthreads();
    }

    float bias[8];
    *reinterpret_cast<float4*>(&bias[0]) = *reinterpret_cast<const float4*>(br + tx * 8);
    *reinterpret_cast<float4*>(&bias[4]) = *reinterpret_cast<const float4*>(br + tx * 8 + 4);

#pragma unroll
    for (int i = 0; i < 8; ++i) {
        const int gnode = row0 + ty * 8 + i;
        if (gnode >= N) continue;
        float o[8];
#pragma unroll
        for (int j = 0; j < 8; ++j) o[j] = fmaxf(acc[i][j] + bias[j], 0.f);
        float* dstp = out + (size_t)gnode * D_FEAT + tx * 8;
        *reinterpret_cast<float4*>(dstp + 0) = *reinterpret_cast<float4*>(&o[0]);
        *reinterpret_cast<float4*>(dstp + 4) = *reinterpret_cast<float4*>(&o[4]);
        if (WRITE_BF16) {
            uint4 pk;
            pk.x = (unsigned)f2bf(o[0]) | ((unsigned)f2bf(o[1]) << 16);
            pk.y = (unsigned)f2bf(o[2]) | ((unsigned)f2bf(o[3]) << 16);
            pk.z = (unsigned)f2bf(o[4]) | ((unsigned)f2bf(o[5]) << 16);
            pk.w = (unsigned)f2bf(o[6]) | ((unsigned)f2bf(o[7]) << 16);
            *reinterpret_cast<uint4*>(hb_out + (size_t)gnode * D_FEAT + tx * 8) = pk;
        }
    }
}

extern "C" void kernel_launch(void* const* d_in, const int* in_sizes, int n_in,
                              void* d_out, int out_size, void* d_ws, size_t ws_size,
                              hipStream_t stream) {
    const float* x  = (const float*)d_in[0];
    const int*   ei = (const int*)d_in[1];     // [2, E] int32 (JAX x64 disabled)
    const float* ew = (const float*)d_in[2];
    const float* Wr0 = (const float*)d_in[3];
    const float* br0 = (const float*)d_in[4];
    const float* Ws0 = (const float*)d_in[5];
    const float* Wr1 = (const float*)d_in[6];
    const float* br1 = (const float*)d_in[7];
    const float* Ws1 = (const float*)d_in[8];

    const int N = in_sizes[0] / D_FEAT;
    const int E = in_sizes[1] / 2;
    const int* src = ei;
    const int* dst = ei + E;

    // ---- workspace carve-up (16B aligned), ~65 MB total ----
    char* w = (char*)d_ws;
    auto carve = [&](size_t bytes) { char* p = w; w += (bytes + 15) & ~(size_t)15; return p; };
    unsigned short* aggb = (unsigned short*)carve((size_t)N * D_FEAT * 2);  // 25.6 MB
    unsigned short* xhb  = (unsigned short*)carve((size_t)N * D_FEAT * 2);  // 25.6 MB (xb, then hb)
    int*   counts  = (int*)  carve((size_t)N * 4);
    int*   row_ptr = (int*)  carve((size_t)(N + 1) * 4);
    int*   pos     = (int*)  carve((size_t)N * 4);
    int*   bsum    = (int*)  carve(128 * 4);
    int*   src_s   = (int*)  carve((size_t)E * 4);                           // 6.4 MB
    float* w_s     = (float*)carve((size_t)E * 4);                           // 6.4 MB

    float* out = (float*)d_out;  // holds intermediate h after layer 0

    const int nb = (N + 1023) / 1024;   // scan blocks (98 for N=100k, <=128)
    const int eb = (E + 255) / 256;
    const int n4 = (N * D_FEAT) / 4;    // divisible (D=128)
    const int gather_blocks = (N + 3) / 4;
    const int gemm_blocks = (N + 127) / 128;

    // ---- CSR build (reused by both layers) ----
    hipMemsetAsync(counts, 0, (size_t)N * 4, stream);
    histogram_kernel<<<eb, 256, 0, stream>>>(dst, counts, E);
    scan_block_sums<<<nb, 256, 0, stream>>>(counts, bsum, N);
    scan_offsets<<<1, 128, 0, stream>>>(bsum, nb, row_ptr, N);
    scan_final<<<nb, 256, 0, stream>>>(counts, bsum, row_ptr, pos, N);
    permute_edges<<<eb, 256, 0, stream>>>(src, dst, ew, pos, src_s, w_s, E);

    // ---- x -> bf16 (gather L0 source) ----
    convert_f32_bf16<<<(n4 + 255) / 256, 256, 0, stream>>>(x, xhb, n4);

    // ---- Layer 0 (weighted) ----
    gather_aggregate<true><<<gather_blocks, 256, 0, stream>>>(xhb, row_ptr, src_s, w_s, aggb, N);
    // xhb dead after this point; GEMM L0 rewrites it with bf16(h)
    gemm_relu_kernel<true><<<gemm_blocks, 256, 0, stream>>>(aggb, x, Wr0, Ws0, br0, out, xhb, N);

    // ---- Layer 1 (unweighted — reference omits edge_weight here) ----
    gather_aggregate<false><<<gather_blocks, 256, 0, stream>>>(xhb, row_ptr, src_s, w_s, aggb, N);
    gemm_relu_kernel<false><<<gemm_blocks, 256, 0, stream>>>(aggb, out, Wr1, Ws1, br1, out, nullptr, N);
}

// Round 6
// 478.829 us; speedup vs baseline: 12.1740x; 1.3603x over previous
//
#include <hip/hip_runtime.h>
#include <hip/hip_bf16.h>

#ifndef D_FEAT
#define D_FEAT 128
#endif

typedef __attribute__((ext_vector_type(8))) short bf16x8;
typedef __attribute__((ext_vector_type(4))) float f32x4;

// ---------------- bf16 helpers (RN-even) ----------------
__device__ __forceinline__ unsigned short f2bf(float f) {
    union { float f; unsigned u; } v; v.f = f;
    unsigned r = v.u + 0x7FFF + ((v.u >> 16) & 1);
    return (unsigned short)(r >> 16);
}
__device__ __forceinline__ float bf2f_lo(unsigned u) {
    union { unsigned u; float f; } v; v.u = u << 16; return v.f;
}
__device__ __forceinline__ float bf2f_hi(unsigned u) {
    union { unsigned u; float f; } v; v.u = u & 0xFFFF0000u; return v.f;
}
__device__ __forceinline__ float bfu(unsigned short s) {
    union { unsigned u; float f; } v; v.u = ((unsigned)s) << 16; return v.f;
}

// ---------------------------------------------------------------------------
// CSR build (per call): counts -> 2-level exclusive scan -> permute edges.
// ---------------------------------------------------------------------------
__global__ void histogram_kernel(const int* __restrict__ dst, int* __restrict__ counts, int E) {
    int e = blockIdx.x * blockDim.x + threadIdx.x;
    if (e < E) atomicAdd(&counts[dst[e]], 1);
}

__global__ void scan_block_sums(const int* __restrict__ counts, int* __restrict__ bsum, int N) {
    __shared__ int red[256];
    const int b = blockIdx.x, t = threadIdx.x;
    const int base = b * 1024 + t * 4;
    int s = 0;
#pragma unroll
    for (int j = 0; j < 4; ++j) { int i = base + j; if (i < N) s += counts[i]; }
    red[t] = s; __syncthreads();
    for (int off = 128; off > 0; off >>= 1) {
        if (t < off) red[t] += red[t + off];
        __syncthreads();
    }
    if (t == 0) bsum[b] = red[0];
}

__global__ void scan_offsets(int* __restrict__ bsum, int nb, int* __restrict__ row_ptr, int N) {
    __shared__ int sh[128];
    const int t = threadIdx.x;
    const int v = (t < nb) ? bsum[t] : 0;
    sh[t] = v; __syncthreads();
    for (int off = 1; off < 128; off <<= 1) {
        int add = (t >= off) ? sh[t - off] : 0;
        __syncthreads();
        sh[t] += add;
        __syncthreads();
    }
    const int incl = sh[t];
    if (t < nb) bsum[t] = incl - v;
    if (t == nb - 1) row_ptr[N] = incl;
}

__global__ void scan_final(const int* __restrict__ counts, const int* __restrict__ bsum,
                           int* __restrict__ row_ptr, int* __restrict__ pos, int N) {
    __shared__ int tsum[256];
    const int b = blockIdx.x, t = threadIdx.x;
    const int base = b * 1024 + t * 4;
    int c[4]; int s = 0;
#pragma unroll
    for (int j = 0; j < 4; ++j) { int i = base + j; c[j] = (i < N) ? counts[i] : 0; s += c[j]; }
    tsum[t] = s; __syncthreads();
    const int v = s;
    for (int off = 1; off < 256; off <<= 1) {
        int add = (t >= off) ? tsum[t - off] : 0;
        __syncthreads();
        tsum[t] += add;
        __syncthreads();
    }
    int excl = tsum[t] - v + bsum[b];
#pragma unroll
    for (int j = 0; j < 4; ++j) {
        int i = base + j;
        if (i < N) { row_ptr[i] = excl; pos[i] = excl; excl += c[j]; }
    }
}

__global__ void permute_edges(const int* __restrict__ src, const int* __restrict__ dst,
                              const float* __restrict__ ew, int* __restrict__ pos,
                              int* __restrict__ src_s, unsigned short* __restrict__ w_s, int E) {
    int e = blockIdx.x * blockDim.x + threadIdx.x;
    if (e >= E) return;
    const int d = dst[e];
    const int p = atomicAdd(&pos[d], 1);
    src_s[p] = src[e];
    w_s[p] = f2bf(ew[e]);
}

// ---------------------------------------------------------------------------
// x fp32 -> bf16 into AX[:,128:256] (thread = 4 elems)
// ---------------------------------------------------------------------------
__global__ void convert_x(const float* __restrict__ x,
                          unsigned short* __restrict__ AX, int N) {
    int i = blockIdx.x * blockDim.x + threadIdx.x;
    if (i >= N * 32) return;
    const int row = i >> 5;
    const int c4 = (i & 31) * 4;
    float4 v = *reinterpret_cast<const float4*>(x + (size_t)row * 128 + c4);
    unsigned lo = (unsigned)f2bf(v.x) | ((unsigned)f2bf(v.y) << 16);
    unsigned hi = (unsigned)f2bf(v.z) | ((unsigned)f2bf(v.w) << 16);
    *reinterpret_cast<uint2*>(AX + (size_t)row * 256 + 128 + c4) = make_uint2(lo, hi);
}

// ---------------------------------------------------------------------------
// Pack W = [Wr;Ws] (256x128 fp32) into canonical B-fragment order, bf16:
// Wp[((ks*8 + ct)*64 + lane)*8 + j] = W[ks*32 + (lane>>4)*8 + j][ct*16 + (lane&15)]
// ---------------------------------------------------------------------------
__global__ void pack_W(const float* __restrict__ Wr, const float* __restrict__ Ws,
                       unsigned short* __restrict__ Wp) {
    int t = blockIdx.x * blockDim.x + threadIdx.x;   // 0..4095
    if (t >= 4096) return;
    const int lane = t & 63;
    const int ct = (t >> 6) & 7;
    const int ks = t >> 9;
    const int col = ct * 16 + (lane & 15);
    const int kbase = ks * 32 + (lane >> 4) * 8;
    unsigned short v[8];
#pragma unroll
    for (int j = 0; j < 8; ++j) {
        const int k = kbase + j;
        const float w = (k < 128) ? Wr[(size_t)k * 128 + col]
                                  : Ws[(size_t)(k - 128) * 128 + col];
        v[j] = f2bf(w);
    }
    *reinterpret_cast<uint4*>(Wp + (size_t)t * 8) = *reinterpret_cast<uint4*>(v);
}

// ---------------------------------------------------------------------------
// Gather-aggregate: one wave per node, 4B (2 bf16 feats) per lane.
// Reads AX[:,128:256] (x or h), writes AX[:,0:128] (agg). Disjoint halves.
// ---------------------------------------------------------------------------
template <bool WEIGHTED>
__global__ void __launch_bounds__(256)
gather_aggregate(const unsigned short* __restrict__ AX,
                 const int* __restrict__ row_ptr,
                 const int* __restrict__ src_s,
                 const unsigned short* __restrict__ w_s,
                 unsigned short* __restrict__ AXagg,   // same buffer, agg half
                 int N) {
    const int node = blockIdx.x * 4 + (threadIdx.x >> 6);
    const int lane = threadIdx.x & 63;
    if (node >= N) return;
    const int beg = row_ptr[node];
    const int end = row_ptr[node + 1];
    float ax = 0.f, ay = 0.f;
    int i = beg;
    for (; i + 2 <= end; i += 2) {
        const int s0 = src_s[i], s1 = src_s[i + 1];
        const float w0 = WEIGHTED ? bfu(w_s[i]) : 1.0f;
        const float w1 = WEIGHTED ? bfu(w_s[i + 1]) : 1.0f;
        const unsigned u0 = *reinterpret_cast<const unsigned*>(AX + (size_t)s0 * 256 + 128 + lane * 2);
        const unsigned u1 = *reinterpret_cast<const unsigned*>(AX + (size_t)s1 * 256 + 128 + lane * 2);
        ax += w0 * bf2f_lo(u0) + w1 * bf2f_lo(u1);
        ay += w0 * bf2f_hi(u0) + w1 * bf2f_hi(u1);
    }
    if (i < end) {
        const int s0 = src_s[i];
        const float w0 = WEIGHTED ? bfu(w_s[i]) : 1.0f;
        const unsigned u0 = *reinterpret_cast<const unsigned*>(AX + (size_t)s0 * 256 + 128 + lane * 2);
        ax += w0 * bf2f_lo(u0);
        ay += w0 * bf2f_hi(u0);
    }
    const unsigned o = (unsigned)f2bf(ax) | ((unsigned)f2bf(ay) << 16);
    *reinterpret_cast<unsigned*>(AXagg + (size_t)node * 256 + lane * 2) = o;
}

// ---------------------------------------------------------------------------
// MFMA GEMM: out = relu(AX @ [Wr;Ws] + br), K=256, bf16 inputs, fp32 acc.
// Block = 4 waves; wave = 32 rows x 128 cols (2x8 fragments, 16x16x32).
// A read directly from global (row-major bf16, 16B/lane frag). No LDS.
// TO_BF16: write h bf16 into AX[:,128:256] only (layer 0).
// else:    write fp32 to out (layer 1).
// ---------------------------------------------------------------------------
template <bool TO_BF16>
__global__ void __launch_bounds__(256)
gemm_mfma(const unsigned short* __restrict__ AX,
          const unsigned short* __restrict__ Wp,
          const float* __restrict__ br,
          float* __restrict__ out,
          unsigned short* __restrict__ AXh,
          int N) {
    const int tid = threadIdx.x;
    const int wave = tid >> 6;
    const int lane = tid & 63;
    const int r0 = blockIdx.x * 128 + wave * 32;
    const int lk = (lane >> 4) * 8;

    int ra = r0 + (lane & 15);
    int rb = ra + 16;
    if (ra >= N) ra = N - 1;   // clamped loads; stores guarded below
    if (rb >= N) rb = N - 1;
    const unsigned short* pa = AX + (size_t)ra * 256 + lk;
    const unsigned short* pb = AX + (size_t)rb * 256 + lk;
    const unsigned short* pw = Wp + (size_t)lane * 8;

    f32x4 acc[2][8];
#pragma unroll
    for (int rt = 0; rt < 2; ++rt)
#pragma unroll
        for (int ct = 0; ct < 8; ++ct)
            acc[rt][ct] = (f32x4){0.f, 0.f, 0.f, 0.f};

#pragma unroll
    for (int ks = 0; ks < 8; ++ks) {
        const bf16x8 a0 = *reinterpret_cast<const bf16x8*>(pa + ks * 32);
        const bf16x8 a1 = *reinterpret_cast<const bf16x8*>(pb + ks * 32);
#pragma unroll
        for (int ct = 0; ct < 8; ++ct) {
            const bf16x8 b = *reinterpret_cast<const bf16x8*>(pw + (((ks << 3) + ct) << 9));
            acc[0][ct] = __builtin_amdgcn_mfma_f32_16x16x32_bf16(a0, b, acc[0][ct], 0, 0, 0);
            acc[1][ct] = __builtin_amdgcn_mfma_f32_16x16x32_bf16(a1, b, acc[1][ct], 0, 0, 0);
        }
    }

    // Epilogue. C/D: col = lane&15, row = (lane>>4)*4 + reg (within 16x16 tile).
    const int crow = (lane >> 4) * 4;
    const int ccol = lane & 15;
#pragma unroll
    for (int ct = 0; ct < 8; ++ct) {
        const int col = ct * 16 + ccol;
        const float bias = br[col];
#pragma unroll
        for (int rt = 0; rt < 2; ++rt) {
#pragma unroll
            for (int reg = 0; reg < 4; ++reg) {
                const int row = r0 + rt * 16 + crow + reg;
                if (row >= N) continue;
                const float v = fmaxf(acc[rt][ct][reg] + bias, 0.f);
                if (TO_BF16) {
                    AXh[(size_t)row * 256 + 128 + col] = f2bf(v);
                } else {
                    out[(size_t)row * 128 + col] = v;
                }
            }
        }
    }
}

extern "C" void kernel_launch(void* const* d_in, const int* in_sizes, int n_in,
                              void* d_out, int out_size, void* d_ws, size_t ws_size,
                              hipStream_t stream) {
    const float* x  = (const float*)d_in[0];
    const int*   ei = (const int*)d_in[1];     // [2, E] int32 (JAX x64 disabled)
    const float* ew = (const float*)d_in[2];
    const float* Wr0 = (const float*)d_in[3];
    const float* br0 = (const float*)d_in[4];
    const float* Ws0 = (const float*)d_in[5];
    const float* Wr1 = (const float*)d_in[6];
    const float* br1 = (const float*)d_in[7];
    const float* Ws1 = (const float*)d_in[8];

    const int N = in_sizes[0] / D_FEAT;
    const int E = in_sizes[1] / 2;
    const int* src = ei;
    const int* dst = ei + E;

    // ---- workspace carve-up (16B aligned), ~62 MB ----
    char* w = (char*)d_ws;
    auto carve = [&](size_t bytes) { char* p = w; w += (bytes + 15) & ~(size_t)15; return p; };
    unsigned short* AX  = (unsigned short*)carve((size_t)N * 256 * 2);  // 51.2 MB
    unsigned short* Wp0 = (unsigned short*)carve(256 * 128 * 2);        // 64 KB
    unsigned short* Wp1 = (unsigned short*)carve(256 * 128 * 2);        // 64 KB
    int*   counts  = (int*)  carve((size_t)N * 4);
    int*   row_ptr = (int*)  carve((size_t)(N + 1) * 4);
    int*   pos     = (int*)  carve((size_t)N * 4);
    int*   bsum    = (int*)  carve(128 * 4);
    int*   src_s   = (int*)  carve((size_t)E * 4);                      // 6.4 MB
    unsigned short* w_s = (unsigned short*)carve((size_t)E * 2);        // 3.2 MB

    float* out = (float*)d_out;

    const int nb = (N + 1023) / 1024;   // scan blocks (98 for N=100k, <=128)
    const int eb = (E + 255) / 256;
    const int gather_blocks = (N + 3) / 4;
    const int gemm_blocks = (N + 127) / 128;

    // ---- CSR build (reused by both layers) ----
    hipMemsetAsync(counts, 0, (size_t)N * 4, stream);
    histogram_kernel<<<eb, 256, 0, stream>>>(dst, counts, E);
    scan_block_sums<<<nb, 256, 0, stream>>>(counts, bsum, N);
    scan_offsets<<<1, 128, 0, stream>>>(bsum, nb, row_ptr, N);
    scan_final<<<nb, 256, 0, stream>>>(counts, bsum, row_ptr, pos, N);
    permute_edges<<<eb, 256, 0, stream>>>(src, dst, ew, pos, src_s, w_s, E);

    // ---- one-time prep: x -> AX[:,128:], W -> packed bf16 fragments ----
    convert_x<<<(N * 32 + 255) / 256, 256, 0, stream>>>(x, AX, N);
    pack_W<<<16, 256, 0, stream>>>(Wr0, Ws0, Wp0);
    pack_W<<<16, 256, 0, stream>>>(Wr1, Ws1, Wp1);

    // ---- Layer 0 (weighted) ----
    gather_aggregate<true><<<gather_blocks, 256, 0, stream>>>(AX, row_ptr, src_s, w_s, AX, N);
    gemm_mfma<true><<<gemm_blocks, 256, 0, stream>>>(AX, Wp0, br0, nullptr, AX, N);

    // ---- Layer 1 (unweighted — reference omits edge_weight here) ----
    gather_aggregate<false><<<gather_blocks, 256, 0, stream>>>(AX, row_ptr, src_s, w_s, AX, N);
    gemm_mfma<false><<<gemm_blocks, 256, 0, stream>>>(AX, Wp1, br1, out, nullptr, N);
}

// Round 7
// 458.315 us; speedup vs baseline: 12.7189x; 1.0448x over previous
//
#include <hip/hip_runtime.h>
#include <hip/hip_bf16.h>

#ifndef D_FEAT
#define D_FEAT 128
#endif

typedef __attribute__((ext_vector_type(8))) short bf16x8;
typedef __attribute__((ext_vector_type(4))) float f32x4;
typedef unsigned long long u64;

// ---------------- bf16 helpers (RN-even) ----------------
__device__ __forceinline__ unsigned short f2bf(float f) {
    union { float f; unsigned u; } v; v.f = f;
    unsigned r = v.u + 0x7FFF + ((v.u >> 16) & 1);
    return (unsigned short)(r >> 16);
}
__device__ __forceinline__ float bf2f_lo(unsigned u) {
    union { unsigned u; float f; } v; v.u = u << 16; return v.f;
}
__device__ __forceinline__ float bf2f_hi(unsigned u) {
    union { unsigned u; float f; } v; v.u = u & 0xFFFF0000u; return v.f;
}
__device__ __forceinline__ float bfu(unsigned short s) {
    union { unsigned u; float f; } v; v.u = ((unsigned)s) << 16; return v.f;
}

// ---------------------------------------------------------------------------
// Per-node histogram + 2-level scan -> row_ptr, pos (insert cursors).
// ---------------------------------------------------------------------------
__global__ void histogram_kernel(const int* __restrict__ dst, int* __restrict__ counts, int E) {
    int e = blockIdx.x * blockDim.x + threadIdx.x;
    if (e < E) atomicAdd(&counts[dst[e]], 1);
}

__global__ void scan_block_sums(const int* __restrict__ counts, int* __restrict__ bsum, int N) {
    __shared__ int red[256];
    const int b = blockIdx.x, t = threadIdx.x;
    const int base = b * 1024 + t * 4;
    int s = 0;
#pragma unroll
    for (int j = 0; j < 4; ++j) { int i = base + j; if (i < N) s += counts[i]; }
    red[t] = s; __syncthreads();
    for (int off = 128; off > 0; off >>= 1) {
        if (t < off) red[t] += red[t + off];
        __syncthreads();
    }
    if (t == 0) bsum[b] = red[0];
}

__global__ void scan_offsets(int* __restrict__ bsum, int nb, int* __restrict__ row_ptr, int N) {
    __shared__ int sh[128];
    const int t = threadIdx.x;
    const int v = (t < nb) ? bsum[t] : 0;
    sh[t] = v; __syncthreads();
    for (int off = 1; off < 128; off <<= 1) {
        int add = (t >= off) ? sh[t - off] : 0;
        __syncthreads();
        sh[t] += add;
        __syncthreads();
    }
    const int incl = sh[t];
    if (t < nb) bsum[t] = incl - v;
    if (t == nb - 1) row_ptr[N] = incl;
}

__global__ void scan_final(const int* __restrict__ counts, const int* __restrict__ bsum,
                           int* __restrict__ row_ptr, int* __restrict__ pos, int N) {
    __shared__ int tsum[256];
    const int b = blockIdx.x, t = threadIdx.x;
    const int base = b * 1024 + t * 4;
    int c[4]; int s = 0;
#pragma unroll
    for (int j = 0; j < 4; ++j) { int i = base + j; c[j] = (i < N) ? counts[i] : 0; s += c[j]; }
    tsum[t] = s; __syncthreads();
    const int v = s;
    for (int off = 1; off < 256; off <<= 1) {
        int add = (t >= off) ? tsum[t - off] : 0;
        __syncthreads();
        tsum[t] += add;
        __syncthreads();
    }
    int excl = tsum[t] - v + bsum[b];
#pragma unroll
    for (int j = 0; j < 4; ++j) {
        int i = base + j;
        if (i < N) { row_ptr[i] = excl; pos[i] = excl; excl += c[j]; }
    }
}

// ---------------------------------------------------------------------------
// 8-way dst-range partition split (deterministic, no global atomics).
// Record: src | dst<<20 | bf16(w)<<40  (N < 2^20).
// ---------------------------------------------------------------------------
#define CHUNK 2048

__global__ void part_count(const int* __restrict__ dst, int E, int Q,
                           int* __restrict__ pcnt) {
    __shared__ int c[8];
    const int t = threadIdx.x;
    if (t < 8) c[t] = 0;
    __syncthreads();
    const int base = blockIdx.x * CHUNK;
    const int lim = min(base + CHUNK, E);
    for (int i = base + t; i < lim; i += 256) atomicAdd(&c[dst[i] / Q], 1);
    __syncthreads();
    if (t < 8) pcnt[blockIdx.x * 8 + t] = c[t];
}

// 8 waves; wave w scans partition w's per-block counts -> per-block offsets.
__global__ void part_scan(const int* __restrict__ pcnt, int nblk,
                          const int* __restrict__ row_ptr, int N, int Q,
                          int* __restrict__ poff) {
    const int wave = threadIdx.x >> 6;
    const int lane = threadIdx.x & 63;
    if (wave >= 8) return;
    int carry = row_ptr[min(wave * Q, N)];
    for (int i0 = 0; i0 < nblk; i0 += 64) {
        const int i = i0 + lane;
        const int v = (i < nblk) ? pcnt[i * 8 + wave] : 0;
        int s = v;
        for (int off = 1; off < 64; off <<= 1) {
            int tsh = __shfl_up(s, off);
            if (lane >= off) s += tsh;
        }
        if (i < nblk) poff[i * 8 + wave] = carry + (s - v);
        carry += __shfl(s, 63);
    }
}

__global__ void part_write(const int* __restrict__ src, const int* __restrict__ dst,
                           const float* __restrict__ ew, const int* __restrict__ poff,
                           u64* __restrict__ stg, int E, int Q) {
    __shared__ int cur[8];
    const int t = threadIdx.x;
    if (t < 8) cur[t] = poff[blockIdx.x * 8 + t];
    __syncthreads();
    const int base = blockIdx.x * CHUNK;
    const int lim = min(base + CHUNK, E);
    for (int i = base + t; i < lim; i += 256) {
        const int d = dst[i];
        const int p = atomicAdd(&cur[d / Q], 1);
        const u64 rec = (u64)(unsigned)src[i] | ((u64)(unsigned)d << 20)
                      | ((u64)f2bf(ew[i]) << 40);
        stg[p] = rec;
    }
}

// Blocks pinned to partition via bid&7 (XCD locality heuristic): scattered
// writes confined to the partition's ~1.6MB region -> L2-resident.
__global__ void part_scatter(const u64* __restrict__ stg,
                             const int* __restrict__ row_ptr, int N, int Q,
                             int* __restrict__ pos, u64* __restrict__ erec) {
    const int p = blockIdx.x & 7;
    const int sub = blockIdx.x >> 3;
    const int nsub = gridDim.x >> 3;
    const int beg = row_ptr[min(p * Q, N)];
    const int end = row_ptr[min((p + 1) * Q, N)];
    for (int i = beg + sub * 256 + threadIdx.x; i < end; i += nsub * 256) {
        const u64 rec = stg[i];
        const int d = (int)((rec >> 20) & 0xFFFFF);
        const int fp = atomicAdd(&pos[d], 1);
        erec[fp] = rec;
    }
}

// ---------------------------------------------------------------------------
// x fp32 -> bf16 into AX[:,128:256]
// ---------------------------------------------------------------------------
__global__ void convert_x(const float* __restrict__ x,
                          unsigned short* __restrict__ AX, int N) {
    int i = blockIdx.x * blockDim.x + threadIdx.x;
    if (i >= N * 32) return;
    const int row = i >> 5;
    const int c4 = (i & 31) * 4;
    float4 v = *reinterpret_cast<const float4*>(x + (size_t)row * 128 + c4);
    unsigned lo = (unsigned)f2bf(v.x) | ((unsigned)f2bf(v.y) << 16);
    unsigned hi = (unsigned)f2bf(v.z) | ((unsigned)f2bf(v.w) << 16);
    *reinterpret_cast<uint2*>(AX + (size_t)row * 256 + 128 + c4) = make_uint2(lo, hi);
}

// ---------------------------------------------------------------------------
// Pack W = [Wr;Ws] (256x128 fp32) into canonical B-fragment order, bf16.
// ---------------------------------------------------------------------------
__global__ void pack_W(const float* __restrict__ Wr, const float* __restrict__ Ws,
                       unsigned short* __restrict__ Wp) {
    int t = blockIdx.x * blockDim.x + threadIdx.x;   // 0..4095
    if (t >= 4096) return;
    const int lane = t & 63;
    const int ct = (t >> 6) & 7;
    const int ks = t >> 9;
    const int col = ct * 16 + (lane & 15);
    const int kbase = ks * 32 + (lane >> 4) * 8;
    unsigned short v[8];
#pragma unroll
    for (int j = 0; j < 8; ++j) {
        const int k = kbase + j;
        const float w = (k < 128) ? Wr[(size_t)k * 128 + col]
                                  : Ws[(size_t)(k - 128) * 128 + col];
        v[j] = f2bf(w);
    }
    *reinterpret_cast<uint4*>(Wp + (size_t)t * 8) = *reinterpret_cast<uint4*>(v);
}

// ---------------------------------------------------------------------------
// Gather-aggregate: one wave per node, 4B (2 bf16 feats) per lane.
// Reads AX[:,128:256] (x or h), writes AX[:,0:128] (agg).
// ---------------------------------------------------------------------------
template <bool WEIGHTED>
__global__ void __launch_bounds__(256)
gather_aggregate(const unsigned short* __restrict__ AX,
                 const int* __restrict__ row_ptr,
                 const u64* __restrict__ erec,
                 unsigned short* __restrict__ AXagg,
                 int N) {
    const int node = blockIdx.x * 4 + (threadIdx.x >> 6);
    const int lane = threadIdx.x & 63;
    if (node >= N) return;
    const int beg = row_ptr[node];
    const int end = row_ptr[node + 1];
    float ax = 0.f, ay = 0.f;
    int i = beg;
    for (; i + 2 <= end; i += 2) {
        const u64 r0 = erec[i], r1 = erec[i + 1];
        const int s0 = (int)(r0 & 0xFFFFF), s1 = (int)(r1 & 0xFFFFF);
        const float w0 = WEIGHTED ? bfu((unsigned short)(r0 >> 40)) : 1.0f;
        const float w1 = WEIGHTED ? bfu((unsigned short)(r1 >> 40)) : 1.0f;
        const unsigned u0 = *reinterpret_cast<const unsigned*>(AX + (size_t)s0 * 256 + 128 + lane * 2);
        const unsigned u1 = *reinterpret_cast<const unsigned*>(AX + (size_t)s1 * 256 + 128 + lane * 2);
        ax += w0 * bf2f_lo(u0) + w1 * bf2f_lo(u1);
        ay += w0 * bf2f_hi(u0) + w1 * bf2f_hi(u1);
    }
    if (i < end) {
        const u64 r0 = erec[i];
        const int s0 = (int)(r0 & 0xFFFFF);
        const float w0 = WEIGHTED ? bfu((unsigned short)(r0 >> 40)) : 1.0f;
        const unsigned u0 = *reinterpret_cast<const unsigned*>(AX + (size_t)s0 * 256 + 128 + lane * 2);
        ax += w0 * bf2f_lo(u0);
        ay += w0 * bf2f_hi(u0);
    }
    const unsigned o = (unsigned)f2bf(ax) | ((unsigned)f2bf(ay) << 16);
    *reinterpret_cast<unsigned*>(AXagg + (size_t)node * 256 + lane * 2) = o;
}

// ---------------------------------------------------------------------------
// MFMA GEMM: out = relu(AX @ [Wr;Ws] + br), K=256, bf16 in, fp32 acc.
// Wave = 32 rows x 128 cols (2x8 fragments of 16x16x32). A direct from global.
// ---------------------------------------------------------------------------
template <bool TO_BF16>
__global__ void __launch_bounds__(256)
gemm_mfma(const unsigned short* __restrict__ AX,
          const unsigned short* __restrict__ Wp,
          const float* __restrict__ br,
          float* __restrict__ out,
          unsigned short* __restrict__ AXh,
          int N) {
    const int tid = threadIdx.x;
    const int wave = tid >> 6;
    const int lane = tid & 63;
    const int r0 = blockIdx.x * 128 + wave * 32;
    const int lk = (lane >> 4) * 8;

    int ra = r0 + (lane & 15);
    int rb = ra + 16;
    if (ra >= N) ra = N - 1;
    if (rb >= N) rb = N - 1;
    const unsigned short* pa = AX + (size_t)ra * 256 + lk;
    const unsigned short* pb = AX + (size_t)rb * 256 + lk;
    const unsigned short* pw = Wp + (size_t)lane * 8;

    f32x4 acc[2][8];
#pragma unroll
    for (int rt = 0; rt < 2; ++rt)
#pragma unroll
        for (int ct = 0; ct < 8; ++ct)
            acc[rt][ct] = (f32x4){0.f, 0.f, 0.f, 0.f};

#pragma unroll
    for (int ks = 0; ks < 8; ++ks) {
        const bf16x8 a0 = *reinterpret_cast<const bf16x8*>(pa + ks * 32);
        const bf16x8 a1 = *reinterpret_cast<const bf16x8*>(pb + ks * 32);
#pragma unroll
        for (int ct = 0; ct < 8; ++ct) {
            const bf16x8 b = *reinterpret_cast<const bf16x8*>(pw + (((ks << 3) + ct) << 9));
            acc[0][ct] = __builtin_amdgcn_mfma_f32_16x16x32_bf16(a0, b, acc[0][ct], 0, 0, 0);
            acc[1][ct] = __builtin_amdgcn_mfma_f32_16x16x32_bf16(a1, b, acc[1][ct], 0, 0, 0);
        }
    }

    const int crow = (lane >> 4) * 4;
    const int ccol = lane & 15;
#pragma unroll
    for (int ct = 0; ct < 8; ++ct) {
        const int col = ct * 16 + ccol;
        const float bias = br[col];
#pragma unroll
        for (int rt = 0; rt < 2; ++rt) {
#pragma unroll
            for (int reg = 0; reg < 4; ++reg) {
                const int row = r0 + rt * 16 + crow + reg;
                if (row >= N) continue;
                const float v = fmaxf(acc[rt][ct][reg] + bias, 0.f);
                if (TO_BF16) {
                    AXh[(size_t)row * 256 + 128 + col] = f2bf(v);
                } else {
                    out[(size_t)row * 128 + col] = v;
                }
            }
        }
    }
}

extern "C" void kernel_launch(void* const* d_in, const int* in_sizes, int n_in,
                              void* d_out, int out_size, void* d_ws, size_t ws_size,
                              hipStream_t stream) {
    const float* x  = (const float*)d_in[0];
    const int*   ei = (const int*)d_in[1];     // [2, E] int32 (JAX x64 disabled)
    const float* ew = (const float*)d_in[2];
    const float* Wr0 = (const float*)d_in[3];
    const float* br0 = (const float*)d_in[4];
    const float* Ws0 = (const float*)d_in[5];
    const float* Wr1 = (const float*)d_in[6];
    const float* br1 = (const float*)d_in[7];
    const float* Ws1 = (const float*)d_in[8];

    const int N = in_sizes[0] / D_FEAT;
    const int E = in_sizes[1] / 2;
    const int* src = ei;
    const int* dst = ei + E;
    const int Q = (N + 7) / 8;          // dst-partition width

    // ---- workspace carve-up (16B aligned), ~79 MB ----
    char* w = (char*)d_ws;
    auto carve = [&](size_t bytes) { char* p = w; w += (bytes + 15) & ~(size_t)15; return p; };
    unsigned short* AX  = (unsigned short*)carve((size_t)N * 256 * 2);  // 51.2 MB
    unsigned short* Wp0 = (unsigned short*)carve(256 * 128 * 2);
    unsigned short* Wp1 = (unsigned short*)carve(256 * 128 * 2);
    int*   counts  = (int*)  carve((size_t)N * 4);
    int*   row_ptr = (int*)  carve((size_t)(N + 1) * 4);
    int*   pos     = (int*)  carve((size_t)N * 4);
    int*   bsum    = (int*)  carve(128 * 4);
    const int nchunk = (E + CHUNK - 1) / CHUNK;
    int*   pcnt    = (int*)  carve((size_t)nchunk * 8 * 4);
    int*   poff    = (int*)  carve((size_t)nchunk * 8 * 4);
    u64*   stg     = (u64*)  carve((size_t)E * 8);                      // 12.8 MB
    u64*   erec    = (u64*)  carve((size_t)E * 8);                      // 12.8 MB

    float* out = (float*)d_out;

    const int nb = (N + 1023) / 1024;
    const int eb = (E + 255) / 256;
    const int gather_blocks = (N + 3) / 4;
    const int gemm_blocks = (N + 127) / 128;

    // ---- CSR build ----
    hipMemsetAsync(counts, 0, (size_t)N * 4, stream);
    histogram_kernel<<<eb, 256, 0, stream>>>(dst, counts, E);
    scan_block_sums<<<nb, 256, 0, stream>>>(counts, bsum, N);
    scan_offsets<<<1, 128, 0, stream>>>(bsum, nb, row_ptr, N);
    scan_final<<<nb, 256, 0, stream>>>(counts, bsum, row_ptr, pos, N);

    // ---- edge reorder: 8-way partition split, then local scatter ----
    part_count<<<nchunk, 256, 0, stream>>>(dst, E, Q, pcnt);
    part_scan<<<1, 512, 0, stream>>>(pcnt, nchunk, row_ptr, N, Q, poff);
    part_write<<<nchunk, 256, 0, stream>>>(src, dst, ew, poff, stg, E, Q);
    part_scatter<<<768, 256, 0, stream>>>(stg, row_ptr, N, Q, pos, erec);

    // ---- one-time prep ----
    convert_x<<<(N * 32 + 255) / 256, 256, 0, stream>>>(x, AX, N);
    pack_W<<<16, 256, 0, stream>>>(Wr0, Ws0, Wp0);
    pack_W<<<16, 256, 0, stream>>>(Wr1, Ws1, Wp1);

    // ---- Layer 0 (weighted) ----
    gather_aggregate<true><<<gather_blocks, 256, 0, stream>>>(AX, row_ptr, erec, AX, N);
    gemm_mfma<true><<<gemm_blocks, 256, 0, stream>>>(AX, Wp0, br0, nullptr, AX, N);

    // ---- Layer 1 (unweighted — reference omits edge_weight here) ----
    gather_aggregate<false><<<gather_blocks, 256, 0, stream>>>(AX, row_ptr, erec, AX, N);
    gemm_mfma<false><<<gemm_blocks, 256, 0, stream>>>(AX, Wp1, br1, out, nullptr, N);
}